// Round 13
// baseline (37.128 us; speedup 1.0000x reference)
//
#include <hip/hip_runtime.h>
#include <hip/hip_bf16.h>

typedef __attribute__((ext_vector_type(8))) short bf16x8;
typedef __attribute__((ext_vector_type(4))) float f32x4;
typedef __attribute__((ext_vector_type(4))) int i32x4;

// RNE round two fp32 -> packed bf16 pair (elem a = low half)
__device__ inline unsigned int pack_bf2(float a, float b) {
    unsigned int ua = __builtin_bit_cast(unsigned int, a);
    unsigned int ub = __builtin_bit_cast(unsigned int, b);
    ua = (ua + 0x7fffu + ((ua >> 16) & 1u)) >> 16;
    ub = (ub + 0x7fffu + ((ub >> 16) & 1u)) >> 16;
    return (ub << 16) | (ua & 0xffffu);
}
// RNE single fp32 -> bf16 (as ushort)
__device__ inline unsigned short f2bf1(float a) {
    unsigned int u = __builtin_bit_cast(unsigned int, a);
    u = (u + 0x7fffu + ((u >> 16) & 1u)) >> 16;
    return (unsigned short)u;
}
// bf16 (ushort) -> fp32, exact
__device__ inline float bf2f(unsigned short u) {
    return __builtin_bit_cast(float, ((unsigned int)u) << 16);
}

// ---------------------------------------------------------------------------
// Kernel 1: repack conv_w [K=768][N=256] fp32 -> bf16 in MFMA B-fragment order.
// FROZEN.
// ---------------------------------------------------------------------------
__global__ void pack_w_kernel(const float* __restrict__ conv_w, i32x4* __restrict__ bpack) {
    int t = blockIdx.x * 256 + threadIdx.x;       // 0 .. 24575
    int lane = t & 63;
    int g = t >> 6;                                // nt*24 + ksg
    int nt = g / 24, ks = g - nt * 24;
    int k0 = ks * 32 + ((lane >> 4) << 3);
    int n  = nt * 16 + (lane & 15);
    const float* src = conv_w + (size_t)k0 * 256 + n;
    float v[8];
#pragma unroll
    for (int j = 0; j < 8; ++j) v[j] = src[(size_t)j * 256];
    i32x4 o;
    o.x = pack_bf2(v[0], v[1]);
    o.y = pack_bf2(v[2], v[3]);
    o.z = pack_bf2(v[4], v[5]);
    o.w = pack_bf2(v[6], v[7]);
    bpack[t] = o;
}

// ---------------------------------------------------------------------------
// Kernel 2 (R13): cold-BW conv. R12 accounting: conv warm = 3us (R11 reps)
// but ~27us in the timed path -> cold L3 (dirty 0xAA poison writebacks +
// HBM latency) with only a shallow in-flight window. Fix: issue EVERY
// global load at the prologue, in CONSUMPTION ORDER (one in-order vmcnt
// queue): B0, s0, B1, s1..s3 -> all 16 image rows in flight immediately
// (12 x f32x4/thread). B double-buffered in regs (BA/BB); B2/B3 refills
// issued right after compute0/compute1. Each stage/compute wait drains
// only already-needed loads; s3 stays in flight until stage3.
// ~183 VGPR -> 1 block/CU (8 waves), grid 512 = 2 rounds. LDS 25.6 KB.
// ---------------------------------------------------------------------------
__global__ __launch_bounds__(512) void conv_kernel(
    const float* __restrict__ images,
    const i32x4* __restrict__ bpack,
    const float* __restrict__ conv_b,
    unsigned short* __restrict__ featB) {
    __shared__ short ldsA[2][32 * 200];   // [buf][patch 0..31][k 0..191, stride 200]

    const int tid  = threadIdx.x;
    const int lane = tid & 63;
    const int w    = tid >> 6;        // wave 0..7 -> N columns w*32..
    const int l15  = lane & 15;
    const int lg   = lane >> 4;       // 0..3

    const int g = blockIdx.x;         // strip 0..511
    const int b = g >> 5, ii = g & 31;

    const int sr = tid >> 7;          // row within chunk (0..3)
    const int tc = tid & 127;
    const float* rowb = images + (size_t)(b * 512 + ii * 16 + sr) * 1536 + tc * 4;

    int widx[3];
#pragma unroll
    for (int p = 0; p < 3; ++p) {
        int f0 = tc * 4 + p * 512;            // float index within image row
        int j = f0 / 48;                      // patch column 0..31
        int off = f0 - 48 * j;                // 0..44, multiple of 4
        widx[p] = j * 200 + sr * 48 + off;
    }

    float bias[2];
#pragma unroll
    for (int sub = 0; sub < 2; ++sub)
        bias[sub] = conv_b[w * 32 + sub * 16 + l15];

    const i32x4* bp = bpack + (size_t)(2 * w * 24) * 64 + lane;

    f32x4 acc[2][2] = {};
    f32x4 s0[3], s1[3], s2[3], s3[3];     // all 4 chunks, statically indexed
    i32x4 BA[2][6], BB[2][6];             // B reg double-buffer

    // ---- prologue: issue order == consumption order ----
    // B0 -> BA (oldest in queue)
#pragma unroll
    for (int sub = 0; sub < 2; ++sub)
#pragma unroll
    for (int s = 0; s < 6; ++s)
        BA[sub][s] = bp[(size_t)(sub * 24 + s) * 64];
    __builtin_amdgcn_sched_barrier(0);
    // s0 (chunk 0 image rows)
#pragma unroll
    for (int p = 0; p < 3; ++p) s0[p] = *(const f32x4*)(rowb + p * 512);
    __builtin_amdgcn_sched_barrier(0);
    // B1 -> BB
#pragma unroll
    for (int sub = 0; sub < 2; ++sub)
#pragma unroll
    for (int s = 0; s < 6; ++s)
        BB[sub][s] = bp[(size_t)(sub * 24 + 6 + s) * 64];
    __builtin_amdgcn_sched_barrier(0);
    // s1, s2, s3 — ALL remaining HBM loads now in flight
#pragma unroll
    for (int p = 0; p < 3; ++p) s1[p] = *(const f32x4*)(rowb + 6144 + p * 512);
#pragma unroll
    for (int p = 0; p < 3; ++p) s2[p] = *(const f32x4*)(rowb + 2 * 6144 + p * 512);
#pragma unroll
    for (int p = 0; p < 3; ++p) s3[p] = *(const f32x4*)(rowb + 3 * 6144 + p * 512);
    __builtin_amdgcn_sched_barrier(0);
    // stage chunk 0 (drains only B0+s0; B1,s1..s3 stay in flight)
#pragma unroll
    for (int p = 0; p < 3; ++p) {
        int2 v;
        v.x = pack_bf2(s0[p].x, s0[p].y);
        v.y = pack_bf2(s0[p].z, s0[p].w);
        *(int2*)(&ldsA[0][widx[p]]) = v;
    }
    asm volatile("s_waitcnt lgkmcnt(0)" ::: "memory");
    __builtin_amdgcn_s_barrier();
    __builtin_amdgcn_sched_barrier(0);

#pragma unroll
    for (int rc = 0; rc < 4; ++rc) {
        // ---- compute chunk rc (B already in regs; LDS ready) ----
        const short* bufA = &ldsA[rc & 1][0];
#pragma unroll
        for (int s = 0; s < 6; ++s) {
            bf16x8 aF0 = *(const bf16x8*)(&bufA[l15 * 200 + s * 32 + lg * 8]);
            bf16x8 aF1 = *(const bf16x8*)(&bufA[(16 + l15) * 200 + s * 32 + lg * 8]);
#pragma unroll
            for (int sub = 0; sub < 2; ++sub) {
                bf16x8 bF = __builtin_bit_cast(bf16x8,
                    ((rc & 1) == 0) ? BA[sub][s] : BB[sub][s]);
                acc[0][sub] = __builtin_amdgcn_mfma_f32_16x16x32_bf16(aF0, bF, acc[0][sub], 0, 0, 0);
                acc[1][sub] = __builtin_amdgcn_mfma_f32_16x16x32_bf16(aF1, bF, acc[1][sub], 0, 0, 0);
            }
        }
        __builtin_amdgcn_sched_barrier(0);
        // ---- refill the just-consumed B buffer ----
        if (rc == 0) {
#pragma unroll
            for (int sub = 0; sub < 2; ++sub)
#pragma unroll
            for (int s = 0; s < 6; ++s)
                BA[sub][s] = bp[(size_t)(sub * 24 + 12 + s) * 64];   // B2
        }
        if (rc == 1) {
#pragma unroll
            for (int sub = 0; sub < 2; ++sub)
#pragma unroll
            for (int s = 0; s < 6; ++s)
                BB[sub][s] = bp[(size_t)(sub * 24 + 18 + s) * 64];   // B3
        }
        __builtin_amdgcn_sched_barrier(0);
        // ---- stage chunk rc+1 from its prologue-issued slot ----
        if (rc == 0) {
#pragma unroll
            for (int p = 0; p < 3; ++p) {
                int2 v;
                v.x = pack_bf2(s1[p].x, s1[p].y);
                v.y = pack_bf2(s1[p].z, s1[p].w);
                *(int2*)(&ldsA[1][widx[p]]) = v;
            }
        }
        if (rc == 1) {
#pragma unroll
            for (int p = 0; p < 3; ++p) {
                int2 v;
                v.x = pack_bf2(s2[p].x, s2[p].y);
                v.y = pack_bf2(s2[p].z, s2[p].w);
                *(int2*)(&ldsA[0][widx[p]]) = v;
            }
        }
        if (rc == 2) {
#pragma unroll
            for (int p = 0; p < 3; ++p) {
                int2 v;
                v.x = pack_bf2(s3[p].x, s3[p].y);
                v.y = pack_bf2(s3[p].z, s3[p].w);
                *(int2*)(&ldsA[1][widx[p]]) = v;
            }
        }
        asm volatile("s_waitcnt lgkmcnt(0)" ::: "memory");
        __builtin_amdgcn_s_barrier();
        __builtin_amdgcn_sched_barrier(0);
    }

    // epilogue: D row in 16-tile = 4*lg + r, col = l15; store bf16
    const int m0 = g * 32;
#pragma unroll
    for (int mt = 0; mt < 2; ++mt)
#pragma unroll
    for (int sub = 0; sub < 2; ++sub)
#pragma unroll
    for (int r = 0; r < 4; ++r) {
        int m = m0 + mt * 16 + lg * 4 + r;
        int n = w * 32 + sub * 16 + l15;
        float v = acc[mt][sub][r] + bias[sub];
        featB[(size_t)m * 256 + n] = f2bf1(fmaxf(v, 0.f));
    }
}

// ---------------------------------------------------------------------------
// Kernel 3 (R12 structure, FROZEN): roi + dense, 1024 threads, 4-way ILP.
// ---------------------------------------------------------------------------
__global__ __launch_bounds__(1024) void roi_dense_kernel(
    const float* __restrict__ bboxes,
    const unsigned short* __restrict__ featB,
    const float* __restrict__ dense_w,
    const float* __restrict__ dense_b,
    float* __restrict__ out) {
    __shared__ int   offs[4][49];
    __shared__ float wts[4][49];
    __shared__ float part[1024];
    __shared__ float objv[256];

    const int bn = blockIdx.x;         // b*16 + n
    const int b  = bn >> 4;
    const int tid = threadIdx.x;
    const int c  = tid & 255;
    const int h  = tid >> 8;           // 0..3

    const float4 box = *(const float4*)(bboxes + (size_t)bn * 4);
    bool empty = (box.x == -1.f) & (box.y == -1.f) & (box.z == -1.f) & (box.w == -1.f);
    if (empty) {
        if (tid < 256) out[(size_t)bn * 256 + tid] = dense_b[tid];
        return;
    }

    if (tid < 49) {
        int sy = tid / 7, sx = tid - sy * 7;
        float py = (box.x + (box.z - box.x) * ((sy + 0.5f) * (1.0f / 7.0f))) * 32.f - 0.5f;
        float px = (box.y + (box.w - box.y) * ((sx + 0.5f) * (1.0f / 7.0f))) * 32.f - 0.5f;
        float y0f = floorf(py), x0f = floorf(px);
        float wy = py - y0f, wx = px - x0f;
        int y0 = min(max((int)y0f, 0), 31);
        int y1 = min(max((int)y0f + 1, 0), 31);
        int x0 = min(max((int)x0f, 0), 31);
        int x1 = min(max((int)x0f + 1, 0), 31);
        offs[0][tid] = (y0 * 32 + x0) * 256;
        offs[1][tid] = (y0 * 32 + x1) * 256;
        offs[2][tid] = (y1 * 32 + x0) * 256;
        offs[3][tid] = (y1 * 32 + x1) * 256;
        wts[0][tid] = (1.f - wy) * (1.f - wx);
        wts[1][tid] = (1.f - wy) * wx;
        wts[2][tid] = wy * (1.f - wx);
        wts[3][tid] = wy * wx;
    }
    __syncthreads();

    // gather: 4-way sample split, 4 independent corner accumulators
    const unsigned short* fb = featB + (size_t)b * (1024 * 256) + c;
    float a0 = 0.f, a1 = 0.f, a2 = 0.f, a3 = 0.f;
    for (int s = h; s < 49; s += 4) {
        a0 += wts[0][s] * bf2f(fb[offs[0][s]]);
        a1 += wts[1][s] * bf2f(fb[offs[1][s]]);
        a2 += wts[2][s] * bf2f(fb[offs[2][s]]);
        a3 += wts[3][s] * bf2f(fb[offs[3][s]]);
    }
    part[tid] = (a0 + a1) + (a2 + a3);
    __syncthreads();
    if (tid < 256)
        objv[tid] = ((part[tid] + part[tid + 256]) + (part[tid + 512] + part[tid + 768]))
                    * (1.f / 49.f);
    __syncthreads();

    // dense: k-split 4 ways, 2 interleaved accumulators
    const float* dwp = dense_w + (size_t)(h * 64) * 256 + c;
    const float* ov  = &objv[h * 64];
    float d0 = 0.f, d1 = 0.f;
#pragma unroll 8
    for (int kk = 0; kk < 64; kk += 2) {
        d0 += ov[kk]     * dwp[(size_t)kk * 256];
        d1 += ov[kk + 1] * dwp[(size_t)(kk + 1) * 256];
    }
    part[tid] = d0 + d1;
    __syncthreads();
    if (tid < 256)
        out[(size_t)bn * 256 + tid] =
            ((part[tid] + part[tid + 256]) + (part[tid + 512] + part[tid + 768]))
            + dense_b[tid];
}

extern "C" void kernel_launch(void* const* d_in, const int* in_sizes, int n_in,
                              void* d_out, int out_size, void* d_ws, size_t ws_size,
                              hipStream_t stream) {
    const float* images  = (const float*)d_in[0];   // [16,512,512,3]
    const float* bboxes  = (const float*)d_in[1];   // [16,16,4]
    const float* conv_w  = (const float*)d_in[2];   // [16,16,3,256]
    const float* conv_b  = (const float*)d_in[3];   // [256]
    const float* dense_w = (const float*)d_in[4];   // [256,256]
    const float* dense_b = (const float*)d_in[5];   // [256]
    float* out = (float*)d_out;

    char* ws = (char*)d_ws;
    i32x4* bpack = (i32x4*)ws;                          // 384 KiB (bf16 B fragments)
    unsigned short* featB = (unsigned short*)(ws + 512 * 1024);  // 16384*256 bf16 = 8.4 MiB

    pack_w_kernel<<<96, 256, 0, stream>>>(conv_w, bpack);
    conv_kernel<<<512, 512, 0, stream>>>(images, bpack, conv_b, featB);
    roi_dense_kernel<<<256, 1024, 0, stream>>>(bboxes, featB, dense_w, dense_b, out);
}

// Round 14
// 36.252 us; speedup vs baseline: 1.0242x; 1.0242x over previous
//
#include <hip/hip_runtime.h>
#include <hip/hip_bf16.h>

typedef __attribute__((ext_vector_type(8))) short bf16x8;
typedef __attribute__((ext_vector_type(4))) float f32x4;
typedef __attribute__((ext_vector_type(4))) int i32x4;

// RNE round two fp32 -> packed bf16 pair (elem a = low half)
__device__ inline unsigned int pack_bf2(float a, float b) {
    unsigned int ua = __builtin_bit_cast(unsigned int, a);
    unsigned int ub = __builtin_bit_cast(unsigned int, b);
    ua = (ua + 0x7fffu + ((ua >> 16) & 1u)) >> 16;
    ub = (ub + 0x7fffu + ((ub >> 16) & 1u)) >> 16;
    return (ub << 16) | (ua & 0xffffu);
}
// RNE single fp32 -> bf16 (as ushort)
__device__ inline unsigned short f2bf1(float a) {
    unsigned int u = __builtin_bit_cast(unsigned int, a);
    u = (u + 0x7fffu + ((u >> 16) & 1u)) >> 16;
    return (unsigned short)u;
}
// bf16 (ushort) -> fp32, exact
__device__ inline float bf2f(unsigned short u) {
    return __builtin_bit_cast(float, ((unsigned int)u) << 16);
}
// non-temporal f32x4 load: no L2/L3 allocation -> no dirty-victim writeback
__device__ inline f32x4 ldnt4(const float* p) {
    return __builtin_nontemporal_load((const f32x4*)p);
}

// ---------------------------------------------------------------------------
// Kernel 1: repack conv_w [K=768][N=256] fp32 -> bf16 in MFMA B-fragment order.
// conv_w read once per replay -> non-temporal.
// ---------------------------------------------------------------------------
__global__ void pack_w_kernel(const float* __restrict__ conv_w, i32x4* __restrict__ bpack) {
    int t = blockIdx.x * 256 + threadIdx.x;       // 0 .. 24575
    int lane = t & 63;
    int g = t >> 6;                                // nt*24 + ksg
    int nt = g / 24, ks = g - nt * 24;
    int k0 = ks * 32 + ((lane >> 4) << 3);
    int n  = nt * 16 + (lane & 15);
    const float* src = conv_w + (size_t)k0 * 256 + n;
    float v[8];
#pragma unroll
    for (int j = 0; j < 8; ++j) v[j] = __builtin_nontemporal_load(src + (size_t)j * 256);
    i32x4 o;
    o.x = pack_bf2(v[0], v[1]);
    o.y = pack_bf2(v[2], v[3]);
    o.z = pack_bf2(v[4], v[5]);
    o.w = pack_bf2(v[6], v[7]);
    bpack[t] = o;
}

// ---------------------------------------------------------------------------
// Kernel 2 (R14): R10/R12 conv structure EXACTLY, + NON-TEMPORAL image loads.
// Images are read exactly once per replay; with L3 left 100% dirty by the
// harness's 256MiB 0xAA fills, cached reads force ~50MB of poison victim
// writebacks. NT loads skip L3 allocation -> no evictions.
// Block 512 thr = 8 waves over N=256; M=32 (one strip/block); grid 512.
// K-chunk=192, counted-wait pipeline, feat stored bf16.
// ---------------------------------------------------------------------------
__global__ __launch_bounds__(512) void conv_kernel(
    const float* __restrict__ images,
    const i32x4* __restrict__ bpack,
    const float* __restrict__ conv_b,
    unsigned short* __restrict__ featB) {
    __shared__ short ldsA[2][32 * 200];   // [buf][patch 0..31][k 0..191, stride 200]

    const int tid  = threadIdx.x;
    const int lane = tid & 63;
    const int w    = tid >> 6;        // wave 0..7 -> N columns w*32..
    const int l15  = lane & 15;
    const int lg   = lane >> 4;       // 0..3

    const int g = blockIdx.x;         // strip 0..511
    const int b = g >> 5, ii = g & 31;

    const int sr = tid >> 7;          // row within chunk (0..3)
    const int tc = tid & 127;
    const float* rowb = images + (size_t)(b * 512 + ii * 16 + sr) * 1536 + tc * 4;

    int widx[3];
#pragma unroll
    for (int p = 0; p < 3; ++p) {
        int f0 = tc * 4 + p * 512;            // float index within image row
        int j = f0 / 48;                      // patch column 0..31
        int off = f0 - 48 * j;                // 0..44, multiple of 4
        widx[p] = j * 200 + sr * 48 + off;
    }

    float bias[2];
#pragma unroll
    for (int sub = 0; sub < 2; ++sub)
        bias[sub] = conv_b[w * 32 + sub * 16 + l15];

    const i32x4* bp = bpack + (size_t)(2 * w * 24) * 64 + lane;

    f32x4 acc[2][2] = {};
    f32x4 sA[3], sB[3];               // 2-deep chunk slots, statically indexed

    // ---- prologue: chunk 0 load+stage; chunk 1 loads in flight in sB ----
    {
        f32x4 t0[3];
#pragma unroll
        for (int p = 0; p < 3; ++p) t0[p] = ldnt4(rowb + p * 512);
#pragma unroll
        for (int p = 0; p < 3; ++p) sB[p] = ldnt4(rowb + 6144 + p * 512);
#pragma unroll
        for (int p = 0; p < 3; ++p) {
            int2 v;
            v.x = pack_bf2(t0[p].x, t0[p].y);
            v.y = pack_bf2(t0[p].z, t0[p].w);
            *(int2*)(&ldsA[0][widx[p]]) = v;
        }
    }
    asm volatile("s_waitcnt lgkmcnt(0)" ::: "memory");
    __builtin_amdgcn_s_barrier();
    __builtin_amdgcn_sched_barrier(0);

#pragma unroll
    for (int rc = 0; rc < 4; ++rc) {
        // (1) B for THIS chunk — issued FIRST (oldest in vmcnt queue)
        i32x4 Bc[2][6];
#pragma unroll
        for (int sub = 0; sub < 2; ++sub)
#pragma unroll
        for (int s = 0; s < 6; ++s)
            Bc[sub][s] = bp[(size_t)(sub * 24 + rc * 6 + s) * 64];
        __builtin_amdgcn_sched_barrier(0);
        // (2) image loads chunk rc+2 -> freed slot (parity-static), NT
        if (rc == 0) {
#pragma unroll
            for (int p = 0; p < 3; ++p) sA[p] = ldnt4(rowb + 2 * 6144 + p * 512);
        }
        if (rc == 1) {
#pragma unroll
            for (int p = 0; p < 3; ++p) sB[p] = ldnt4(rowb + 3 * 6144 + p * 512);
        }
        // (3) compute chunk rc
        const short* bufA = &ldsA[rc & 1][0];
#pragma unroll
        for (int s = 0; s < 6; ++s) {
            bf16x8 aF0 = *(const bf16x8*)(&bufA[l15 * 200 + s * 32 + lg * 8]);
            bf16x8 aF1 = *(const bf16x8*)(&bufA[(16 + l15) * 200 + s * 32 + lg * 8]);
#pragma unroll
            for (int sub = 0; sub < 2; ++sub) {
                bf16x8 bF = __builtin_bit_cast(bf16x8, Bc[sub][s]);
                acc[0][sub] = __builtin_amdgcn_mfma_f32_16x16x32_bf16(aF0, bF, acc[0][sub], 0, 0, 0);
                acc[1][sub] = __builtin_amdgcn_mfma_f32_16x16x32_bf16(aF1, bF, acc[1][sub], 0, 0, 0);
            }
        }
        __builtin_amdgcn_sched_barrier(0);
        // (4) stage chunk rc+1 from the slot loaded one iteration ago
        if (rc < 3) {
            short* dst = &ldsA[(rc + 1) & 1][0];
            if ((rc & 1) == 0) {
#pragma unroll
                for (int p = 0; p < 3; ++p) {
                    int2 v;
                    v.x = pack_bf2(sB[p].x, sB[p].y);
                    v.y = pack_bf2(sB[p].z, sB[p].w);
                    *(int2*)(&dst[widx[p]]) = v;
                }
            } else {
#pragma unroll
                for (int p = 0; p < 3; ++p) {
                    int2 v;
                    v.x = pack_bf2(sA[p].x, sA[p].y);
                    v.y = pack_bf2(sA[p].z, sA[p].w);
                    *(int2*)(&dst[widx[p]]) = v;
                }
            }
        }
        // (5) LDS visibility + barrier; image loads stay in flight
        asm volatile("s_waitcnt lgkmcnt(0)" ::: "memory");
        __builtin_amdgcn_s_barrier();
        __builtin_amdgcn_sched_barrier(0);
    }

    // epilogue: D row in 16-tile = 4*lg + r, col = l15; store bf16
    const int m0 = g * 32;
#pragma unroll
    for (int mt = 0; mt < 2; ++mt)
#pragma unroll
    for (int sub = 0; sub < 2; ++sub)
#pragma unroll
    for (int r = 0; r < 4; ++r) {
        int m = m0 + mt * 16 + lg * 4 + r;
        int n = w * 32 + sub * 16 + l15;
        float v = acc[mt][sub][r] + bias[sub];
        featB[(size_t)m * 256 + n] = f2bf1(fmaxf(v, 0.f));
    }
}

// ---------------------------------------------------------------------------
// Kernel 3 (R12 structure, FROZEN): roi + dense, 1024 threads, 4-way ILP.
// ---------------------------------------------------------------------------
__global__ __launch_bounds__(1024) void roi_dense_kernel(
    const float* __restrict__ bboxes,
    const unsigned short* __restrict__ featB,
    const float* __restrict__ dense_w,
    const float* __restrict__ dense_b,
    float* __restrict__ out) {
    __shared__ int   offs[4][49];
    __shared__ float wts[4][49];
    __shared__ float part[1024];
    __shared__ float objv[256];

    const int bn = blockIdx.x;         // b*16 + n
    const int b  = bn >> 4;
    const int tid = threadIdx.x;
    const int c  = tid & 255;
    const int h  = tid >> 8;           // 0..3

    const float4 box = *(const float4*)(bboxes + (size_t)bn * 4);
    bool empty = (box.x == -1.f) & (box.y == -1.f) & (box.z == -1.f) & (box.w == -1.f);
    if (empty) {
        if (tid < 256) out[(size_t)bn * 256 + tid] = dense_b[tid];
        return;
    }

    if (tid < 49) {
        int sy = tid / 7, sx = tid - sy * 7;
        float py = (box.x + (box.z - box.x) * ((sy + 0.5f) * (1.0f / 7.0f))) * 32.f - 0.5f;
        float px = (box.y + (box.w - box.y) * ((sx + 0.5f) * (1.0f / 7.0f))) * 32.f - 0.5f;
        float y0f = floorf(py), x0f = floorf(px);
        float wy = py - y0f, wx = px - x0f;
        int y0 = min(max((int)y0f, 0), 31);
        int y1 = min(max((int)y0f + 1, 0), 31);
        int x0 = min(max((int)x0f, 0), 31);
        int x1 = min(max((int)x0f + 1, 0), 31);
        offs[0][tid] = (y0 * 32 + x0) * 256;
        offs[1][tid] = (y0 * 32 + x1) * 256;
        offs[2][tid] = (y1 * 32 + x0) * 256;
        offs[3][tid] = (y1 * 32 + x1) * 256;
        wts[0][tid] = (1.f - wy) * (1.f - wx);
        wts[1][tid] = (1.f - wy) * wx;
        wts[2][tid] = wy * (1.f - wx);
        wts[3][tid] = wy * wx;
    }
    __syncthreads();

    // gather: 4-way sample split, 4 independent corner accumulators
    const unsigned short* fb = featB + (size_t)b * (1024 * 256) + c;
    float a0 = 0.f, a1 = 0.f, a2 = 0.f, a3 = 0.f;
    for (int s = h; s < 49; s += 4) {
        a0 += wts[0][s] * bf2f(fb[offs[0][s]]);
        a1 += wts[1][s] * bf2f(fb[offs[1][s]]);
        a2 += wts[2][s] * bf2f(fb[offs[2][s]]);
        a3 += wts[3][s] * bf2f(fb[offs[3][s]]);
    }
    part[tid] = (a0 + a1) + (a2 + a3);
    __syncthreads();
    if (tid < 256)
        objv[tid] = ((part[tid] + part[tid + 256]) + (part[tid + 512] + part[tid + 768]))
                    * (1.f / 49.f);
    __syncthreads();

    // dense: k-split 4 ways, 2 interleaved accumulators
    const float* dwp = dense_w + (size_t)(h * 64) * 256 + c;
    const float* ov  = &objv[h * 64];
    float d0 = 0.f, d1 = 0.f;
#pragma unroll 8
    for (int kk = 0; kk < 64; kk += 2) {
        d0 += ov[kk]     * dwp[(size_t)kk * 256];
        d1 += ov[kk + 1] * dwp[(size_t)(kk + 1) * 256];
    }
    part[tid] = d0 + d1;
    __syncthreads();
    if (tid < 256)
        out[(size_t)bn * 256 + tid] =
            ((part[tid] + part[tid + 256]) + (part[tid + 512] + part[tid + 768]))
            + dense_b[tid];
}

extern "C" void kernel_launch(void* const* d_in, const int* in_sizes, int n_in,
                              void* d_out, int out_size, void* d_ws, size_t ws_size,
                              hipStream_t stream) {
    const float* images  = (const float*)d_in[0];   // [16,512,512,3]
    const float* bboxes  = (const float*)d_in[1];   // [16,16,4]
    const float* conv_w  = (const float*)d_in[2];   // [16,16,3,256]
    const float* conv_b  = (const float*)d_in[3];   // [256]
    const float* dense_w = (const float*)d_in[4];   // [256,256]
    const float* dense_b = (const float*)d_in[5];   // [256]
    float* out = (float*)d_out;

    char* ws = (char*)d_ws;
    i32x4* bpack = (i32x4*)ws;                          // 384 KiB (bf16 B fragments)
    unsigned short* featB = (unsigned short*)(ws + 512 * 1024);  // 16384*256 bf16 = 8.4 MiB

    pack_w_kernel<<<96, 256, 0, stream>>>(conv_w, bpack);
    conv_kernel<<<512, 512, 0, stream>>>(images, bpack, conv_b, featB);
    roi_dense_kernel<<<256, 1024, 0, stream>>>(bboxes, featB, dense_w, dense_b, out);
}

// Round 15
// 34.369 us; speedup vs baseline: 1.0803x; 1.0548x over previous
//
#include <hip/hip_runtime.h>
#include <hip/hip_bf16.h>

typedef __attribute__((ext_vector_type(8))) short bf16x8;
typedef __attribute__((ext_vector_type(4))) float f32x4;
typedef __attribute__((ext_vector_type(4))) int i32x4;

// RNE round two fp32 -> packed bf16 pair (elem a = low half)
__device__ inline unsigned int pack_bf2(float a, float b) {
    unsigned int ua = __builtin_bit_cast(unsigned int, a);
    unsigned int ub = __builtin_bit_cast(unsigned int, b);
    ua = (ua + 0x7fffu + ((ua >> 16) & 1u)) >> 16;
    ub = (ub + 0x7fffu + ((ub >> 16) & 1u)) >> 16;
    return (ub << 16) | (ua & 0xffffu);
}
// RNE single fp32 -> bf16 (as ushort)
__device__ inline unsigned short f2bf1(float a) {
    unsigned int u = __builtin_bit_cast(unsigned int, a);
    u = (u + 0x7fffu + ((u >> 16) & 1u)) >> 16;
    return (unsigned short)u;
}
// bf16 (ushort) -> fp32, exact
__device__ inline float bf2f(unsigned short u) {
    return __builtin_bit_cast(float, ((unsigned int)u) << 16);
}

// ---------------------------------------------------------------------------
// Kernel 1: repack conv_w [K=768][N=256] fp32 -> bf16 in MFMA B-fragment order.
// Bpack frag index t = (nt*24 + ksg)*64 + lane, 8 bf16 per t (one int4).
// B[k][n]: k = ksg*32 + (lane>>4)*8 + j, n = nt*16 + (lane&15).
// ---------------------------------------------------------------------------
__global__ void pack_w_kernel(const float* __restrict__ conv_w, i32x4* __restrict__ bpack) {
    int t = blockIdx.x * 256 + threadIdx.x;       // 0 .. 24575
    int lane = t & 63;
    int g = t >> 6;                                // nt*24 + ksg
    int nt = g / 24, ks = g - nt * 24;
    int k0 = ks * 32 + ((lane >> 4) << 3);
    int n  = nt * 16 + (lane & 15);
    const float* src = conv_w + (size_t)k0 * 256 + n;
    float v[8];
#pragma unroll
    for (int j = 0; j < 8; ++j) v[j] = src[(size_t)j * 256];
    i32x4 o;
    o.x = pack_bf2(v[0], v[1]);
    o.y = pack_bf2(v[2], v[3]);
    o.z = pack_bf2(v[4], v[5]);
    o.w = pack_bf2(v[6], v[7]);
    bpack[t] = o;
}

// ---------------------------------------------------------------------------
// Kernel 2 (R15 = R12 exact): conv stem, counted-wait pipeline.
// Block 512 thr = 8 waves over N=256; M=32 (one strip/block); grid 512.
// K-chunk=192 (4 image rows), 4 chunks, LDS double-buffered (25.6 KB).
// B loaded per-chunk (issued first, L2-fast); image loads 2 chunks deep in
// named register slots, staying in flight across raw s_barrier +
// lgkmcnt(0)-only waits. feat stored bf16 (8.4 MB).
// conv_timed ~27us is the environmental floor: 50.3 MB compulsory cold read
// + ~58 MB dirty-poison L3 writebacks + 8.4 MB write at mixed-stream BW;
// 7 schedule variants (R4..R14) all within +-2us of this line.
// ---------------------------------------------------------------------------
__global__ __launch_bounds__(512) void conv_kernel(
    const float* __restrict__ images,
    const i32x4* __restrict__ bpack,
    const float* __restrict__ conv_b,
    unsigned short* __restrict__ featB) {
    __shared__ short ldsA[2][32 * 200];   // [buf][patch 0..31][k 0..191, stride 200]

    const int tid  = threadIdx.x;
    const int lane = tid & 63;
    const int w    = tid >> 6;        // wave 0..7 -> N columns w*32..
    const int l15  = lane & 15;
    const int lg   = lane >> 4;       // 0..3

    const int g = blockIdx.x;         // strip 0..511
    const int b = g >> 5, ii = g & 31;

    const int sr = tid >> 7;          // row within chunk (0..3)
    const int tc = tid & 127;
    const float* rowb = images + (size_t)(b * 512 + ii * 16 + sr) * 1536 + tc * 4;

    int widx[3];
#pragma unroll
    for (int p = 0; p < 3; ++p) {
        int f0 = tc * 4 + p * 512;            // float index within image row
        int j = f0 / 48;                      // patch column 0..31
        int off = f0 - 48 * j;                // 0..44, multiple of 4
        widx[p] = j * 200 + sr * 48 + off;
    }

    float bias[2];
#pragma unroll
    for (int sub = 0; sub < 2; ++sub)
        bias[sub] = conv_b[w * 32 + sub * 16 + l15];

    const i32x4* bp = bpack + (size_t)(2 * w * 24) * 64 + lane;

    f32x4 acc[2][2] = {};
    f32x4 sA[3], sB[3];               // 2-deep chunk slots, statically indexed

    // ---- prologue: chunk 0 load+stage; chunk 1 loads in flight in sB ----
    {
        f32x4 t0[3];
#pragma unroll
        for (int p = 0; p < 3; ++p) t0[p] = *(const f32x4*)(rowb + p * 512);
#pragma unroll
        for (int p = 0; p < 3; ++p) sB[p] = *(const f32x4*)(rowb + 6144 + p * 512);
#pragma unroll
        for (int p = 0; p < 3; ++p) {
            int2 v;
            v.x = pack_bf2(t0[p].x, t0[p].y);
            v.y = pack_bf2(t0[p].z, t0[p].w);
            *(int2*)(&ldsA[0][widx[p]]) = v;
        }
    }
    asm volatile("s_waitcnt lgkmcnt(0)" ::: "memory");
    __builtin_amdgcn_s_barrier();
    __builtin_amdgcn_sched_barrier(0);

#pragma unroll
    for (int rc = 0; rc < 4; ++rc) {
        // (1) B for THIS chunk — issued FIRST (oldest in vmcnt queue)
        i32x4 Bc[2][6];
#pragma unroll
        for (int sub = 0; sub < 2; ++sub)
#pragma unroll
        for (int s = 0; s < 6; ++s)
            Bc[sub][s] = bp[(size_t)(sub * 24 + rc * 6 + s) * 64];
        __builtin_amdgcn_sched_barrier(0);
        // (2) image loads chunk rc+2 -> freed slot (parity-static)
        if (rc == 0) {
#pragma unroll
            for (int p = 0; p < 3; ++p) sA[p] = *(const f32x4*)(rowb + 2 * 6144 + p * 512);
        }
        if (rc == 1) {
#pragma unroll
            for (int p = 0; p < 3; ++p) sB[p] = *(const f32x4*)(rowb + 3 * 6144 + p * 512);
        }
        // (3) compute chunk rc
        const short* bufA = &ldsA[rc & 1][0];
#pragma unroll
        for (int s = 0; s < 6; ++s) {
            bf16x8 aF0 = *(const bf16x8*)(&bufA[l15 * 200 + s * 32 + lg * 8]);
            bf16x8 aF1 = *(const bf16x8*)(&bufA[(16 + l15) * 200 + s * 32 + lg * 8]);
#pragma unroll
            for (int sub = 0; sub < 2; ++sub) {
                bf16x8 bF = __builtin_bit_cast(bf16x8, Bc[sub][s]);
                acc[0][sub] = __builtin_amdgcn_mfma_f32_16x16x32_bf16(aF0, bF, acc[0][sub], 0, 0, 0);
                acc[1][sub] = __builtin_amdgcn_mfma_f32_16x16x32_bf16(aF1, bF, acc[1][sub], 0, 0, 0);
            }
        }
        __builtin_amdgcn_sched_barrier(0);
        // (4) stage chunk rc+1 from the slot loaded one iteration ago
        if (rc < 3) {
            short* dst = &ldsA[(rc + 1) & 1][0];
            if ((rc & 1) == 0) {
#pragma unroll
                for (int p = 0; p < 3; ++p) {
                    int2 v;
                    v.x = pack_bf2(sB[p].x, sB[p].y);
                    v.y = pack_bf2(sB[p].z, sB[p].w);
                    *(int2*)(&dst[widx[p]]) = v;
                }
            } else {
#pragma unroll
                for (int p = 0; p < 3; ++p) {
                    int2 v;
                    v.x = pack_bf2(sA[p].x, sA[p].y);
                    v.y = pack_bf2(sA[p].z, sA[p].w);
                    *(int2*)(&dst[widx[p]]) = v;
                }
            }
        }
        // (5) LDS visibility + barrier; image loads stay in flight
        asm volatile("s_waitcnt lgkmcnt(0)" ::: "memory");
        __builtin_amdgcn_s_barrier();
        __builtin_amdgcn_sched_barrier(0);
    }

    // epilogue: D row in 16-tile = 4*lg + r, col = l15; store bf16
    const int m0 = g * 32;
#pragma unroll
    for (int mt = 0; mt < 2; ++mt)
#pragma unroll
    for (int sub = 0; sub < 2; ++sub)
#pragma unroll
    for (int r = 0; r < 4; ++r) {
        int m = m0 + mt * 16 + lg * 4 + r;
        int n = w * 32 + sub * 16 + l15;
        float v = acc[mt][sub][r] + bias[sub];
        featB[(size_t)m * 256 + n] = f2bf1(fmaxf(v, 0.f));
    }
}

// ---------------------------------------------------------------------------
// Kernel 3 (R12 structure, FROZEN): roi + dense, 1024 threads, 4-way ILP.
// ---------------------------------------------------------------------------
__global__ __launch_bounds__(1024) void roi_dense_kernel(
    const float* __restrict__ bboxes,
    const unsigned short* __restrict__ featB,
    const float* __restrict__ dense_w,
    const float* __restrict__ dense_b,
    float* __restrict__ out) {
    __shared__ int   offs[4][49];
    __shared__ float wts[4][49];
    __shared__ float part[1024];
    __shared__ float objv[256];

    const int bn = blockIdx.x;         // b*16 + n
    const int b  = bn >> 4;
    const int tid = threadIdx.x;
    const int c  = tid & 255;
    const int h  = tid >> 8;           // 0..3

    const float4 box = *(const float4*)(bboxes + (size_t)bn * 4);
    bool empty = (box.x == -1.f) & (box.y == -1.f) & (box.z == -1.f) & (box.w == -1.f);
    if (empty) {
        if (tid < 256) out[(size_t)bn * 256 + tid] = dense_b[tid];
        return;
    }

    if (tid < 49) {
        int sy = tid / 7, sx = tid - sy * 7;
        float py = (box.x + (box.z - box.x) * ((sy + 0.5f) * (1.0f / 7.0f))) * 32.f - 0.5f;
        float px = (box.y + (box.w - box.y) * ((sx + 0.5f) * (1.0f / 7.0f))) * 32.f - 0.5f;
        float y0f = floorf(py), x0f = floorf(px);
        float wy = py - y0f, wx = px - x0f;
        int y0 = min(max((int)y0f, 0), 31);
        int y1 = min(max((int)y0f + 1, 0), 31);
        int x0 = min(max((int)x0f, 0), 31);
        int x1 = min(max((int)x0f + 1, 0), 31);
        offs[0][tid] = (y0 * 32 + x0) * 256;
        offs[1][tid] = (y0 * 32 + x1) * 256;
        offs[2][tid] = (y1 * 32 + x0) * 256;
        offs[3][tid] = (y1 * 32 + x1) * 256;
        wts[0][tid] = (1.f - wy) * (1.f - wx);
        wts[1][tid] = (1.f - wy) * wx;
        wts[2][tid] = wy * (1.f - wx);
        wts[3][tid] = wy * wx;
    }
    __syncthreads();

    // gather: 4-way sample split, 4 independent corner accumulators
    const unsigned short* fb = featB + (size_t)b * (1024 * 256) + c;
    float a0 = 0.f, a1 = 0.f, a2 = 0.f, a3 = 0.f;
    for (int s = h; s < 49; s += 4) {
        a0 += wts[0][s] * bf2f(fb[offs[0][s]]);
        a1 += wts[1][s] * bf2f(fb[offs[1][s]]);
        a2 += wts[2][s] * bf2f(fb[offs[2][s]]);
        a3 += wts[3][s] * bf2f(fb[offs[3][s]]);
    }
    part[tid] = (a0 + a1) + (a2 + a3);
    __syncthreads();
    if (tid < 256)
        objv[tid] = ((part[tid] + part[tid + 256]) + (part[tid + 512] + part[tid + 768]))
                    * (1.f / 49.f);
    __syncthreads();

    // dense: k-split 4 ways, 2 interleaved accumulators
    const float* dwp = dense_w + (size_t)(h * 64) * 256 + c;
    const float* ov  = &objv[h * 64];
    float d0 = 0.f, d1 = 0.f;
#pragma unroll 8
    for (int kk = 0; kk < 64; kk += 2) {
        d0 += ov[kk]     * dwp[(size_t)kk * 256];
        d1 += ov[kk + 1] * dwp[(size_t)(kk + 1) * 256];
    }
    part[tid] = d0 + d1;
    __syncthreads();
    if (tid < 256)
        out[(size_t)bn * 256 + tid] =
            ((part[tid] + part[tid + 256]) + (part[tid + 512] + part[tid + 768]))
            + dense_b[tid];
}

extern "C" void kernel_launch(void* const* d_in, const int* in_sizes, int n_in,
                              void* d_out, int out_size, void* d_ws, size_t ws_size,
                              hipStream_t stream) {
    const float* images  = (const float*)d_in[0];   // [16,512,512,3]
    const float* bboxes  = (const float*)d_in[1];   // [16,16,4]
    const float* conv_w  = (const float*)d_in[2];   // [16,16,3,256]
    const float* conv_b  = (const float*)d_in[3];   // [256]
    const float* dense_w = (const float*)d_in[4];   // [256,256]
    const float* dense_b = (const float*)d_in[5];   // [256]
    float* out = (float*)d_out;

    char* ws = (char*)d_ws;
    i32x4* bpack = (i32x4*)ws;                          // 384 KiB (bf16 B fragments)
    unsigned short* featB = (unsigned short*)(ws + 512 * 1024);  // 16384*256 bf16 = 8.4 MiB

    pack_w_kernel<<<96, 256, 0, stream>>>(conv_w, bpack);
    conv_kernel<<<512, 512, 0, stream>>>(images, bpack, conv_b, featB);
    roi_dense_kernel<<<256, 1024, 0, stream>>>(bboxes, featB, dense_w, dense_b, out);
}